// Round 18
// baseline (236.737 us; speedup 1.0000x reference)
//
#include <hip/hip_runtime.h>
#include <math.h>

// ---------------------------------------------------------------------------
// ConvCaps fused pipeline, MFMA v15 — R18: 256-row tiles, half the phases.
// R17 post-mortem: setprio null, g-float4 null; gemm_fused plateaued 114.5us
// across all sync/occupancy variants => per-block-phase overhead suspected.
// R18: BM=256 BN=128, 512thr/8 waves (wave tile still 64x64 -> same per-CU
// per-phase work), grid 256 = 1 block/CU uniform; phases/CU 288->144.
// Ring-3 (72KB), counted vmcnt(3), fused epilogue. m201-adjacent structure.
// Everything else from R17 (passed, 215.2us, absmax 0.0156).
// ---------------------------------------------------------------------------

typedef unsigned short u16;
typedef __attribute__((ext_vector_type(8))) short short8;
typedef __attribute__((ext_vector_type(4))) float f32x4;
typedef __attribute__((ext_vector_type(16))) float f32x16;

#define MFMA16(a, b, c) __builtin_amdgcn_mfma_f32_16x16x32_bf16(a, b, c, 0, 0, 0)
#define MFMA32(a, b, c) __builtin_amdgcn_mfma_f32_32x32x16_bf16(a, b, c, 0, 0, 0)
#define SB0() __builtin_amdgcn_sched_barrier(0)

#define LN_EPS 1e-8f

// f32 region offsets (float index)
#define O_MU    0
#define O_RSTD  256
#define O_W2    512
#define O_BN1S  1536
#define O_BN1B  1824
#define O_BN2S  2112
#define O_BN2B  2656
#define O_ZB    3200     // 64 zero floats (OOB staging target)

// byte offsets of big regions
#define O_G_B     16384ull                       // u16[16777216]  (33.5 MB)
#define O_AACT_B  (O_G_B + 33554432ull)          // u16[8192*320]  (5.24 MB)
#define O_PART_B  (O_AACT_B + 5242880ull)        // f32[8192*544]  (17.8 MB) conv2 partial
#define O_WF_B    (O_PART_B + 17825792ull)       // u16[8*144*4096] (9.44 MB)
#define O_WA_B    (O_WF_B + 9437184ull)          // u16[6*5*6144]  (0.37 MB)

__device__ __forceinline__ u16 f2bf(float f) {
  union { float f; unsigned u; } v; v.f = f;
  unsigned r = (v.u + 0x7fffu + ((v.u >> 16) & 1u)) >> 16;
  return (u16)r;
}

__device__ __forceinline__ void gll16(const void* g, void* l) {
  __builtin_amdgcn_global_load_lds(
      (const __attribute__((address_space(1))) unsigned int*)g,
      (__attribute__((address_space(3))) unsigned int*)l, 16, 0, 0);
}

// slot swizzle: row/col r, logical 16B-quarter q -> phys slot q ^ sfun(r).
// injective within each 8-row bank-half -> 2-way bank floor (R13-verified: 0).
__device__ __forceinline__ int sfun(int r) { return (r >> 1) & 3; }

// ---------------------------------------------------------------------------
__global__ __launch_bounds__(256) void prep_kernel(
    const float* __restrict__ wts, const float* __restrict__ gamma,
    const float* __restrict__ bn1s, const float* __restrict__ bn1bi,
    const float* __restrict__ bn1m, const float* __restrict__ bn1v,
    const float* __restrict__ bn2s, const float* __restrict__ bn2bi,
    const float* __restrict__ bn2m, const float* __restrict__ bn2v,
    float* __restrict__ ws)
{
  __shared__ float wsm[32 * 33];
  __shared__ float gs[32];
  int t = threadIdx.x;
  if (t < 33) {
    float mx = -1e30f;
    for (int c = 0; c < 32; ++c) mx = fmaxf(mx, wts[c * 33 + t]);
    float sum = 0.f;
    for (int c = 0; c < 32; ++c) {
      float e = expf(wts[c * 33 + t] - mx);
      wsm[c * 33 + t] = e; sum += e;
    }
    float inv = 1.f / sum;
    for (int c = 0; c < 32; ++c) wsm[c * 33 + t] *= inv;
  }
  if (t == 64) {
    float mx = -1e30f;
    for (int d = 0; d < 32; ++d) mx = fmaxf(mx, gamma[d]);
    for (int d = 0; d < 32; ++d) { float e = expf(gamma[d] - mx); gs[d] = e; }
    float sum = 0.f;
    for (int d = 0; d < 32; ++d) sum += gs[d];
    float inv = 1.f / sum;
    for (int d = 0; d < 32; ++d) gs[d] *= inv;
  }
  __syncthreads();
  for (int i = t; i < 1024; i += 256) {
    int c = i >> 5, d = i & 31;
    ws[O_W2 + i] = (wsm[c * 33 + d] + wsm[c * 33 + 32] * gs[d]) * gamma[d];
  }
  for (int i = t; i < 288; i += 256) {
    float s = bn1s[i] / sqrtf(bn1v[i] + 1e-5f);
    ws[O_BN1S + i] = s;
    ws[O_BN1B + i] = bn1bi[i] - bn1m[i] * s;
  }
  for (int i = t; i < 544; i += 256) {
    float s = bn2s[i] / sqrtf(bn2v[i] + 1e-5f);
    ws[O_BN2S + i] = s;
    ws[O_BN2B + i] = bn2bi[i] - bn2m[i] * s;
  }
  if (t < 64) ws[O_ZB + t] = 0.f;
}

// ---------------------------------------------------------------------------
// Stats: one 1024-thread block per (b,cb) — 16 waves for latency hiding.
__global__ __launch_bounds__(1024) void stats_kernel(
    const float* __restrict__ x, float* __restrict__ ws, u16* __restrict__ Aact)
{
  int g = blockIdx.x;
  int b = g >> 5, cb = g & 31;
  const float* base = x + (((size_t)(b * 544 + cb * 16)) << 12);
  float s = 0.f, q = 0.f;
  for (int idx = threadIdx.x; idx < 65536; idx += 1024) {
    int p = idx & 4095;
    int hi = p >> 6, wi = p & 63;
    float wh = ((hi & 1) && hi != 63) ? 2.f : 1.f;
    float ww = ((wi & 1) && wi != 63) ? 2.f : 1.f;
    float v = base[idx];
    float wgt = wh * ww;
    s += wgt * v;
    q += wgt * v * v;
  }
  __shared__ float sb[1024], qb[1024];
  int t = threadIdx.x;
  sb[t] = s; qb[t] = q;
  __syncthreads();
  for (int off = 512; off > 0; off >>= 1) {
    if (t < off) { sb[t] += sb[t + off]; qb[t] += qb[t + off]; }
    __syncthreads();
  }
  if (t == 0) {
    const float N = 147456.f;
    float mean = sb[0] / N;
    float var = (qb[0] - sb[0] * sb[0] / N) / (N - 1.f);
    ws[O_MU + g] = mean;
    ws[O_RSTD + g] = 1.f / sqrtf(var + LN_EPS);
  }
  {
    int pos = (g << 5) + (t >> 5);
    Aact[(size_t)pos * 320 + 288 + (t & 31)] = 0;
  }
}

// ---------------------------------------------------------------------------
// Wf layout (unchanged): per (nt,ch) an 8KB LDS image (nt 0..7; cols>=832 0):
//   u16 idx = (((nt*144+ch)*128 + c)*4 + p)*8 + e,
//   holding k = ch*32 + (p^sfun(c))*8 + e for output col o = nt*128 + c.
// Wa layout unchanged (R4 mapping, consumed by gemm_act).
__global__ __launch_bounds__(256) void wcvt_kernel(
    const float* __restrict__ w1, const float* __restrict__ w2,
    u16* __restrict__ Wf, u16* __restrict__ Wa)
{
  int sid = blockIdx.x * 256 + threadIdx.x;   // < 612864 exactly
  if (sid < 589824) {                         // 8*144*512
    int nt = sid / 73728, rem = sid - nt * 73728;   // 144*512
    int ch = rem / 512, r2 = rem - ch * 512;
    int c = r2 >> 2, p = r2 & 3;
    int o = nt * 128 + c;
    int q = p ^ ((c >> 1) & 3);               // matches sfun(c)
    int kf = (ch << 5) + (q << 3);
    u16* dst = Wf + (size_t)sid * 8;
#pragma unroll
    for (int e = 0; e < 8; ++e) {
      int k = kf + e;
      float v = 0.f;
      if (o < 288) v = w1[(size_t)o * 4608 + k];
      else if (o < 832) v = w2[(size_t)(o - 288) * 4896 + k];
      dst[e] = f2bf(v);
    }
  } else if (sid < 612864) {
    int s2 = sid - 589824;                    // < 23040
    int cb = s2 / 768, si = s2 - cb * 768;
    int ob = cb / 5, ch = cb - ob * 5;
    int nt = si >> 8, ks = (si >> 6) & 3, l2 = si & 63;
    int o = ob * 96 + (nt << 5) + (l2 & 31);
    int kf = (ch << 6) + (ks << 4) + ((l2 >> 5) << 3);
    u16* dst = Wa + (size_t)s2 * 8;
#pragma unroll
    for (int e = 0; e < 8; ++e) {
      int k = kf + e;
      float v = (o < 544 && k < 288) ? w2[(size_t)o * 4896 + 4608 + k] : 0.f;
      dst[e] = f2bf(v);
    }
  }
}

// ---------------------------------------------------------------------------
__global__ __launch_bounds__(256) void g_kernel(
    const float* __restrict__ x, const float* __restrict__ ws,
    u16* __restrict__ Gb)
{
  __shared__ __align__(16) float raw[16][545];
  __shared__ __align__(16) float ut[16][576];
  __shared__ float w2s[1024];
  __shared__ float mus[32], rss[32];
  int t = threadIdx.x;
  int pb = blockIdx.x;
  int b = pb >> 8, hi = (pb >> 2) & 63, wi0 = (pb & 3) << 4;

  {  // float4 loads — lane covers 4 adjacent pixels of one channel.
    int ch4 = t >> 2, wl4 = (t & 3) << 2;
    size_t gbase = ((size_t)b * 544) << 12;
    size_t rowoff = ((size_t)hi << 6) + (size_t)(wi0 + wl4);
    for (int it = 0; it < 9; ++it) {
      int ch = it * 64 + ch4;
      if (ch < 544) {
        float4 v = *reinterpret_cast<const float4*>(
            &x[gbase + ((size_t)ch << 12) + rowoff]);
        raw[wl4 + 0][ch] = v.x;
        raw[wl4 + 1][ch] = v.y;
        raw[wl4 + 2][ch] = v.z;
        raw[wl4 + 3][ch] = v.w;
      }
    }
  }
  for (int i = t; i < 1024; i += 256) w2s[i] = ws[O_W2 + i];
  if (t < 32) { mus[t] = ws[O_MU + b * 32 + t]; rss[t] = ws[O_RSTD + b * 32 + t]; }
  __syncthreads();

  {
    int dl = t & 15, psp = t >> 4;
    for (int it = 0; it < 32; ++it) {
      int pix = it >> 1, half = it & 1;
      int dp = half * 16 + dl;
      int j = (dp << 4) + psp;
      int cbv = j & 31, psv = j >> 5;
      float val = (raw[pix][(cbv << 4) + psv] - mus[cbv]) * rss[cbv];
      ut[pix][psp * 36 + dp] = raw[pix][512 + dp] * val;
    }
  }
  __syncthreads();

  {
    int c0 = t >> 4, psp = t & 15;
    float w2a[32], w2b[32];
#pragma unroll
    for (int d = 0; d < 32; ++d) {
      w2a[d] = w2s[c0 * 32 + d];
      w2b[d] = w2s[(c0 + 16) * 32 + d];
    }
    u16* Gp = Gb + ((size_t)((((b << 6) + hi) << 6) + wi0)) * 512;
    for (int pix = 0; pix < 16; ++pix) {
      float acc0 = 0.f, acc1 = 0.f;
      const float* up = &ut[pix][psp * 36];
#pragma unroll
      for (int k = 0; k < 8; ++k) {
        float4 u4 = *reinterpret_cast<const float4*>(up + 4 * k);
        acc0 = fmaf(w2a[4 * k + 0], u4.x, acc0);
        acc0 = fmaf(w2a[4 * k + 1], u4.y, acc0);
        acc0 = fmaf(w2a[4 * k + 2], u4.z, acc0);
        acc0 = fmaf(w2a[4 * k + 3], u4.w, acc0);
        acc1 = fmaf(w2b[4 * k + 0], u4.x, acc1);
        acc1 = fmaf(w2b[4 * k + 1], u4.y, acc1);
        acc1 = fmaf(w2b[4 * k + 2], u4.z, acc1);
        acc1 = fmaf(w2b[4 * k + 3], u4.w, acc1);
      }
      u16* gp = Gp + (size_t)pix * 512;
      gp[t] = f2bf(acc0);
      gp[256 + t] = f2bf(acc1);
    }
  }
}

// ---------------------------------------------------------------------------
// Fused GEMM v15: M=8192 (32 mt of 256 rows), N=1024 (8 nt, nt=7 zero-pad),
// K=4608 (144 BK=32 steps). Grid 256 = 8 xcd x 4 mloc x 8 nt = 1 block/CU,
// zero tail. 512 thr = 8 waves (4m x 2n), wave tile 64x64 (unchanged ratio).
// RING-3 counted-vmcnt (per-wave 3 loads/stage: 2 A + 1 B -> vmcnt(3)).
// LDS 72 KB: A 3x16KB + B 3x8KB, injective slot swizzle (0 conflicts).
// Epilogue: plain stores — o<288: BN1+sigmoid -> Aact; 288<=o<832: partC2.
__global__ __launch_bounds__(512) void gemm_fused(
    const u16* __restrict__ Gb, const u16* __restrict__ Wf,
    const float* __restrict__ wsf, u16* __restrict__ Aact,
    float* __restrict__ partC2)
{
  __shared__ __align__(16) u16 AlA[3][8192];   // 16 KB each: row r at u16 r*32
  __shared__ __align__(16) u16 AlB[3][4096];   // 8 KB each: col c at u16 c*32
  const int t = threadIdx.x;
  const int w = t >> 6, l = t & 63;
  const int wtm = w & 3, wtn = w >> 2;      // 4m x 2n wave grid
  int bx = blockIdx.x;
  int xcd = bx & 7, idx = bx >> 3;          // idx < 32
  int mloc = idx & 3, nt = idx >> 2;        // mloc 0..3, nt 0..7
  int mt = (xcd << 2) + mloc;               // 0..31
  int p0 = mt << 8;                         // 256 rows per tile

  // A staging precompute: group g covers rows [w*32+g*16, +16)
  size_t pixb[2]; int hb[2], wb[2], qa[2], dofA[2];
#pragma unroll
  for (int g = 0; g < 2; ++g) {
    int r = (w << 5) + (g << 4) + (l >> 2);
    int pos = p0 + r;
    int b_ = pos >> 10, h_ = (pos >> 5) & 31, w_ = pos & 31;
    pixb[g] = ((size_t)b_) << 12;
    hb[g] = 2 * h_ - 1;
    wb[g] = 2 * w_ - 1;
    qa[g] = (((l & 3) ^ sfun(r)) << 3);          // source k-quarter (u16)
    dofA[g] = ((w << 5) + (g << 4)) * 32 + (l << 3);  // linear LDS dest (u16)
  }
  // B staging precompute: wave w covers cols [w*16, +16), 1 gll16/lane
  const int dofB = (w << 9) + (l << 3);          // linear LDS dest (u16)
  const u16* zb = (const u16*)(wsf + O_ZB);
  const u16* wfslab = Wf + ((size_t)(nt * 144)) * 4096;

  // read-offset precompute (loop-invariant): 4 A rows, 4 B cols
  int aoffs[4], boffs[4];
#pragma unroll
  for (int f = 0; f < 4; ++f) {
    int r = (wtm << 6) + (f << 4) + (l & 15);
    aoffs[f] = r * 32 + ((((l >> 4)) ^ sfun(r)) << 3);
    int c = (wtn << 6) + (f << 4) + (l & 15);
    boffs[f] = c * 32 + ((((l >> 4)) ^ sfun(c)) << 3);
  }

  f32x4 acc[4][4];
#pragma unroll
  for (int i = 0; i < 4; ++i)
#pragma unroll
    for (int j = 0; j < 4; ++j) acc[i][j] = (f32x4){0.f, 0.f, 0.f, 0.f};

  auto stage = [&](int ch, int buf) {       // exactly 3 gll16 per wave
    int tap = ch >> 4;
    int kh = tap / 3, kw = tap - kh * 3;
    int cbase = (ch & 15) << 5;
#pragma unroll
    for (int g = 0; g < 2; ++g) {
      int hi = hb[g] + kh, wi = wb[g] + kw;
      bool ok = ((unsigned)hi < 64u) && ((unsigned)wi < 64u);
      const u16* src = ok
          ? (Gb + ((pixb[g] + ((size_t)hi << 6) + (size_t)wi) << 9) + cbase + qa[g])
          : (zb + qa[g]);
      gll16(src, &AlA[buf][dofA[g]]);
    }
    const u16* wsrc = wfslab + ((size_t)ch << 12);
    gll16(wsrc + dofB, &AlB[buf][dofB]);
  };

  // prologue: stage phases 0,1 into ring slots 0,1 (6 loads in flight/wave)
  stage(0, 0);
  stage(1, 1);

  int buf = 0;
  for (int n = 0; n < 144; ++n) {
    SB0();
    if (n < 143) asm volatile("s_waitcnt vmcnt(3)" ::: "memory");
    else         asm volatile("s_waitcnt vmcnt(0)" ::: "memory");
    SB0();
    __builtin_amdgcn_s_barrier();
    SB0();
    if (n + 2 < 144) {
      int nb = (buf >= 1) ? buf - 1 : 2;    // (buf+2)%3
      stage(n + 2, nb);
    }
    SB0();
    short8 aF[4], bF[4];
#pragma unroll
    for (int f = 0; f < 4; ++f) {
      aF[f] = *(const short8*)&AlA[buf][aoffs[f]];
      bF[f] = *(const short8*)&AlB[buf][boffs[f]];
    }
    __builtin_amdgcn_s_setprio(1);
#pragma unroll
    for (int fm = 0; fm < 4; ++fm)
#pragma unroll
      for (int fn = 0; fn < 4; ++fn)
        acc[fm][fn] = MFMA16(aF[fm], bF[fn], acc[fm][fn]);
    __builtin_amdgcn_s_setprio(0);
    buf = (buf == 2) ? 0 : buf + 1;
  }

  // epilogue: plain stores. C/D 16x16: col=l&15, row=(l>>4)*4+reg.
  const float* s1 = wsf + O_BN1S;
  const float* b1 = wsf + O_BN1B;
#pragma unroll
  for (int fn = 0; fn < 4; ++fn) {
    int o = nt * 128 + (wtn << 6) + (fn << 4) + (l & 15);
    if (o < 288) {
      float sc = s1[o], bi = b1[o];
#pragma unroll
      for (int fm = 0; fm < 4; ++fm) {
        int posr = p0 + (wtm << 6) + (fm << 4) + ((l >> 4) << 2);
#pragma unroll
        for (int r = 0; r < 4; ++r) {
          float z = acc[fm][fn][r] * sc + bi;
          float sg = 1.f / (1.f + expf(-z));
          Aact[(size_t)(posr + r) * 320 + o] = f2bf(sg);
        }
      }
    } else if (o < 832) {
#pragma unroll
      for (int fm = 0; fm < 4; ++fm) {
        int posr = p0 + (wtm << 6) + (fm << 4) + ((l >> 4) << 2);
#pragma unroll
        for (int r = 0; r < 4; ++r)
          partC2[(size_t)(posr + r) * 544 + (o - 288)] = acc[fm][fn][r];
      }
    }
  }
}

// ---------------------------------------------------------------------------
// Act GEMM: M=8192, N=576, K=320 (5 chunks). R8/R9 structure (unchanged).
__global__ __launch_bounds__(256, 2) void gemm_act(
    const u16* __restrict__ Aact, const u16* __restrict__ Wa,
    const float* __restrict__ partial, const float* __restrict__ wsf,
    float* __restrict__ outp)
{
  __shared__ __align__(16) char lraw[57344];          // 56 KB
  u16 (*AlA)[128 * 64] = (u16 (*)[128 * 64])lraw;     // 2 x 16 KB
  u16 (*AlB)[6144] = (u16 (*)[6144])(lraw + 32768);   // 2 x 12 KB
  float* T = (float*)lraw;                            // epilogue transpose
  const int t = threadIdx.x;
  const int wid = t >> 6, l = t & 63;
  int bx = blockIdx.x;
  int xcd = bx & 7, idx = bx >> 3;          // idx < 48
  int mt = xcd + ((idx & 7) << 3);
  int ob = idx >> 3;                        // 0..5
  int p0 = mt << 7;

  const u16* abase[4];
  int srow[4];
#pragma unroll
  for (int s = 0; s < 4; ++s) {
    int r = (wid << 5) + (s << 3) + (l >> 3);
    int jsw = ((l & 7) ^ (r & 7)) << 3;
    srow[s] = (wid << 5) + (s << 3);
    abase[s] = Aact + (size_t)(p0 + r) * 320 + jsw;
  }
  const u16* wslice = Wa + (size_t)(ob * 5) * 6144;
  const int bsub = (wid << 9) + (l << 3);

  f32x16 acc0 = {}, acc1 = {}, acc2 = {};

  auto stageA = [&](int ch, u16* lbuf) {
#pragma unroll
    for (int s = 0; s < 4; ++s)
      gll16(abase[s] + (ch << 6), lbuf + (srow[s] << 6));
  };
  auto stageB = [&](int ch, u16* lbuf) {
    const u16* src = wslice + (size_t)ch * 6144 + bsub;
#pragma unroll
    for (int c = 0; c < 3; ++c)
      gll16(src + (c << 11), lbuf + (c << 11) + (wid << 9));
  };
  const int rr = (wid << 5) + (l & 31);
  auto ldsA = [&](const u16* lbuf, short8* av) {
#pragma unroll
    for (int ks = 0; ks < 4; ++ks) {
      int jl = (ks << 1) + (l >> 5);
      av[ks] = *(const short8*)(lbuf + (rr << 6) + ((jl ^ (rr & 7)) << 3));
    }
  };
  auto ldsB = [&](const u16* lbuf, short8* bf) {
#pragma unroll
    for (int k2 = 0; k2 < 12; ++k2)
      bf[k2] = *(const short8*)(lbuf + (k2 << 9) + (l << 3));
  };
  auto mfmaR = [&](const short8* av, const short8* bf) {
    __builtin_amdgcn_s_setprio(1);
#pragma unroll
    for (int ks = 0; ks < 4; ++ks) {
      acc0 = MFMA32(av[ks], bf[ks], acc0);
      acc1 = MFMA32(av[ks], bf[4 + ks], acc1);
      acc2 = MFMA32(av[ks], bf[8 + ks], acc2);
    }
    __builtin_amdgcn_s_setprio(0);
  };

  short8 av[4], bf[12];

  stageA(0, AlA[0]);
  stageB(0, AlB[0]);
  asm volatile("s_waitcnt vmcnt(0)" ::: "memory");
  __builtin_amdgcn_s_barrier();

#define APHASE(K, CUR, NXT)                                                   \
  SB0();                                                                      \
  if ((K) + 1 < 5) { stageA((K) + 1, AlA[NXT]); stageB((K) + 1, AlB[NXT]); }  \
  SB0();                                                                      \
  ldsA(AlA[CUR], av);                                                         \
  ldsB(AlB[CUR], bf);                                                         \
  SB0();                                                                      \
  mfmaR(av, bf);                                                              \
  SB0();                                                                      \
  asm volatile("s_waitcnt vmcnt(0)" ::: "memory");                            \
  __builtin_amdgcn_s_barrier();

  APHASE(0, 0, 1);
  APHASE(1, 1, 0);
  APHASE(2, 0, 1);
  APHASE(3, 1, 0);
  APHASE(4, 0, 1);
#undef APHASE

  __syncthreads();   // protect T-union overwrite of staging LDS

  const float* s2p = wsf + O_BN2S;
  const float* b2p = wsf + O_BN2B;
#pragma unroll
  for (int nt = 0; nt < 3; ++nt) {
    int ol = (nt << 5) + (l & 31);
    int o = ob * 96 + ol;
    float sc = 0.f, bi = 0.f;
    if (o < 544) { sc = s2p[o]; bi = b2p[o]; }
    f32x16 a = (nt == 0) ? acc0 : ((nt == 1) ? acc1 : acc2);
#pragma unroll
    for (int reg = 0; reg < 16; ++reg) {
      int rowD = (reg & 3) + ((reg >> 2) << 3) + ((l >> 5) << 2);
      int pos = p0 + (wid << 5) + rowD;
      float pz = 0.f;
      if (o < 544) pz = partial[(size_t)pos * 544 + o];
      float z = (a[reg] + pz) * sc + bi;
      T[ol * 129 + (wid << 5) + rowD] = fmaxf(z, 0.f);
    }
  }
  __syncthreads();
  for (int s2 = t; s2 < 3072; s2 += 256) {
    int ol = s2 >> 5, c4 = s2 & 31;
    int o = ob * 96 + ol;
    if (o < 544) {
      int pos0 = p0 + (c4 << 2);
      int bb = pos0 >> 10, hw0 = pos0 & 1023;
      int base = ol * 129 + (c4 << 2);
      float4 v;
      v.x = T[base]; v.y = T[base + 1]; v.z = T[base + 2]; v.w = T[base + 3];
      *(float4*)&outp[(((size_t)(bb * 544 + o)) << 10) + hw0] = v;
    }
  }
}

// ---------------------------------------------------------------------------
extern "C" void kernel_launch(void* const* d_in, const int* in_sizes, int n_in,
                              void* d_out, int out_size, void* d_ws,
                              size_t ws_size, hipStream_t stream)
{
  const float* x       = (const float*)d_in[0];
  const float* wts     = (const float*)d_in[1];
  const float* gamma   = (const float*)d_in[2];
  const float* conv1_w = (const float*)d_in[3];
  const float* bn1s    = (const float*)d_in[4];
  const float* bn1b    = (const float*)d_in[5];
  const float* bn1m    = (const float*)d_in[6];
  const float* bn1v    = (const float*)d_in[7];
  const float* conv2_w = (const float*)d_in[8];
  const float* bn2s    = (const float*)d_in[9];
  const float* bn2b    = (const float*)d_in[10];
  const float* bn2m    = (const float*)d_in[11];
  const float* bn2v    = (const float*)d_in[12];

  char* wsb = (char*)d_ws;
  float* wsf = (float*)d_ws;
  u16* Gb    = (u16*)(wsb + O_G_B);
  u16* Aact  = (u16*)(wsb + O_AACT_B);
  float* prt = (float*)(wsb + O_PART_B);
  u16* Wf    = (u16*)(wsb + O_WF_B);
  u16* Wa    = (u16*)(wsb + O_WA_B);
  float* out = (float*)d_out;

  prep_kernel<<<1, 256, 0, stream>>>(wts, gamma, bn1s, bn1b, bn1m, bn1v,
                                     bn2s, bn2b, bn2m, bn2v, wsf);
  stats_kernel<<<256, 1024, 0, stream>>>(x, wsf, Aact);
  wcvt_kernel<<<2394, 256, 0, stream>>>(conv1_w, conv2_w, Wf, Wa);
  g_kernel<<<2048, 256, 0, stream>>>(x, wsf, Gb);
  gemm_fused<<<256, 512, 0, stream>>>(Gb, Wf, wsf, Aact, prt);
  gemm_act<<<384, 256, 0, stream>>>(Aact, Wa, prt, wsf, out);
}

// Round 19
// 205.373 us; speedup vs baseline: 1.1527x; 1.1527x over previous
//
#include <hip/hip_runtime.h>
#include <math.h>

// ---------------------------------------------------------------------------
// ConvCaps fused pipeline, MFMA v16 — R19: W2eff folded into weights.
// R18 post-mortem: 256-row tile regressed (134us); gemm_fused declared at
// structural plateau 114.5us -> reverted to R15/R17 config exactly.
// R19 lever (tail): G = (W2eff (x) I16) u  =>  fold W2eff into conv weights
// (exact f32 fold in wcvt; identical rounding count). g_kernel's heavy
// matmul phase (128 b128 reads + 1024 fmaf/thread) DELETED; g now emits u
// directly (bf16, coalesced). gemm_fused reads Ub with unchanged indexing.
// Wa path split into tiny wa_cvt kernel. Others unchanged.
// ---------------------------------------------------------------------------

typedef unsigned short u16;
typedef __attribute__((ext_vector_type(8))) short short8;
typedef __attribute__((ext_vector_type(4))) float f32x4;
typedef __attribute__((ext_vector_type(16))) float f32x16;

#define MFMA16(a, b, c) __builtin_amdgcn_mfma_f32_16x16x32_bf16(a, b, c, 0, 0, 0)
#define MFMA32(a, b, c) __builtin_amdgcn_mfma_f32_32x32x16_bf16(a, b, c, 0, 0, 0)
#define SB0() __builtin_amdgcn_sched_barrier(0)

#define LN_EPS 1e-8f

// f32 region offsets (float index)
#define O_MU    0
#define O_RSTD  256
#define O_W2    512
#define O_BN1S  1536
#define O_BN1B  1824
#define O_BN2S  2112
#define O_BN2B  2656
#define O_ZB    3200     // 64 zero floats (OOB staging target)

// byte offsets of big regions
#define O_G_B     16384ull                       // u16[16777216]  Ub (33.5 MB)
#define O_AACT_B  (O_G_B + 33554432ull)          // u16[8192*320]  (5.24 MB)
#define O_PART_B  (O_AACT_B + 5242880ull)        // f32[8192*544]  (17.8 MB) conv2 partial
#define O_WF_B    (O_PART_B + 17825792ull)       // u16[8*144*4096] (9.44 MB)
#define O_WA_B    (O_WF_B + 9437184ull)          // u16[6*5*6144]  (0.37 MB)

__device__ __forceinline__ u16 f2bf(float f) {
  union { float f; unsigned u; } v; v.f = f;
  unsigned r = (v.u + 0x7fffu + ((v.u >> 16) & 1u)) >> 16;
  return (u16)r;
}

__device__ __forceinline__ void gll16(const void* g, void* l) {
  __builtin_amdgcn_global_load_lds(
      (const __attribute__((address_space(1))) unsigned int*)g,
      (__attribute__((address_space(3))) unsigned int*)l, 16, 0, 0);
}

// slot swizzle: row/col r, logical 16B-quarter q -> phys slot q ^ sfun(r).
// injective within each 8-row bank-half -> 2-way bank floor (R13-verified: 0).
__device__ __forceinline__ int sfun(int r) { return (r >> 1) & 3; }

// ---------------------------------------------------------------------------
__global__ __launch_bounds__(256) void prep_kernel(
    const float* __restrict__ wts, const float* __restrict__ gamma,
    const float* __restrict__ bn1s, const float* __restrict__ bn1bi,
    const float* __restrict__ bn1m, const float* __restrict__ bn1v,
    const float* __restrict__ bn2s, const float* __restrict__ bn2bi,
    const float* __restrict__ bn2m, const float* __restrict__ bn2v,
    float* __restrict__ ws)
{
  __shared__ float wsm[32 * 33];
  __shared__ float gs[32];
  int t = threadIdx.x;
  if (t < 33) {
    float mx = -1e30f;
    for (int c = 0; c < 32; ++c) mx = fmaxf(mx, wts[c * 33 + t]);
    float sum = 0.f;
    for (int c = 0; c < 32; ++c) {
      float e = expf(wts[c * 33 + t] - mx);
      wsm[c * 33 + t] = e; sum += e;
    }
    float inv = 1.f / sum;
    for (int c = 0; c < 32; ++c) wsm[c * 33 + t] *= inv;
  }
  if (t == 64) {
    float mx = -1e30f;
    for (int d = 0; d < 32; ++d) mx = fmaxf(mx, gamma[d]);
    for (int d = 0; d < 32; ++d) { float e = expf(gamma[d] - mx); gs[d] = e; }
    float sum = 0.f;
    for (int d = 0; d < 32; ++d) sum += gs[d];
    float inv = 1.f / sum;
    for (int d = 0; d < 32; ++d) gs[d] *= inv;
  }
  __syncthreads();
  for (int i = t; i < 1024; i += 256) {
    int c = i >> 5, d = i & 31;
    ws[O_W2 + i] = (wsm[c * 33 + d] + wsm[c * 33 + 32] * gs[d]) * gamma[d];
  }
  for (int i = t; i < 288; i += 256) {
    float s = bn1s[i] / sqrtf(bn1v[i] + 1e-5f);
    ws[O_BN1S + i] = s;
    ws[O_BN1B + i] = bn1bi[i] - bn1m[i] * s;
  }
  for (int i = t; i < 544; i += 256) {
    float s = bn2s[i] / sqrtf(bn2v[i] + 1e-5f);
    ws[O_BN2S + i] = s;
    ws[O_BN2B + i] = bn2bi[i] - bn2m[i] * s;
  }
  if (t < 64) ws[O_ZB + t] = 0.f;
}

// ---------------------------------------------------------------------------
// Stats: one 1024-thread block per (b,cb) — 16 waves for latency hiding.
__global__ __launch_bounds__(1024) void stats_kernel(
    const float* __restrict__ x, float* __restrict__ ws, u16* __restrict__ Aact)
{
  int g = blockIdx.x;
  int b = g >> 5, cb = g & 31;
  const float* base = x + (((size_t)(b * 544 + cb * 16)) << 12);
  float s = 0.f, q = 0.f;
  for (int idx = threadIdx.x; idx < 65536; idx += 1024) {
    int p = idx & 4095;
    int hi = p >> 6, wi = p & 63;
    float wh = ((hi & 1) && hi != 63) ? 2.f : 1.f;
    float ww = ((wi & 1) && wi != 63) ? 2.f : 1.f;
    float v = base[idx];
    float wgt = wh * ww;
    s += wgt * v;
    q += wgt * v * v;
  }
  __shared__ float sb[1024], qb[1024];
  int t = threadIdx.x;
  sb[t] = s; qb[t] = q;
  __syncthreads();
  for (int off = 512; off > 0; off >>= 1) {
    if (t < off) { sb[t] += sb[t + off]; qb[t] += qb[t + off]; }
    __syncthreads();
  }
  if (t == 0) {
    const float N = 147456.f;
    float mean = sb[0] / N;
    float var = (qb[0] - sb[0] * sb[0] / N) / (N - 1.f);
    ws[O_MU + g] = mean;
    ws[O_RSTD + g] = 1.f / sqrtf(var + LN_EPS);
  }
  {
    int pos = (g << 5) + (t >> 5);
    Aact[(size_t)pos * 320 + 288 + (t & 31)] = 0;
  }
}

// ---------------------------------------------------------------------------
// wcvt (R19): folded weights. For o<832, tap<9:
//   Wfold[o][tap*512 + d*16+ps] = sum_c w[o][tap*512 + c*16+ps] * W2eff[c][d]
// written bf16 into the frag-swizzled Wf layout (same layout as before:
//   per (nt,ch) 8KB image, slot p holds logical quarter p^sfun(cc)).
// Rows o in [832,1024) zero-padded. Grid 9216 = 1024 o x 9 taps.
__global__ __launch_bounds__(256) void wcvt_kernel(
    const float* __restrict__ w1, const float* __restrict__ w2,
    const float* __restrict__ wsf, u16* __restrict__ Wf)
{
  __shared__ float rowl[512];
  __shared__ float w2l[1024];
  int bid = blockIdx.x;            // < 9216
  int o = bid / 9, tap = bid - (bid / 9) * 9;
  int t = threadIdx.x;
  int nt = o >> 7, cc = o & 127;
  if (o < 832) {
    const float* src = (o < 288)
        ? (w1 + (size_t)o * 4608 + tap * 512)
        : (w2 + (size_t)(o - 288) * 4896 + tap * 512);
    rowl[t] = src[t];
    rowl[t + 256] = src[t + 256];
    w2l[t] = wsf[O_W2 + t];
    w2l[t + 256] = wsf[O_W2 + t + 256];
    w2l[t + 512] = wsf[O_W2 + t + 512];
    w2l[t + 768] = wsf[O_W2 + t + 768];
    __syncthreads();
#pragma unroll
    for (int i = 0; i < 2; ++i) {
      int j = (t << 1) + i;              // u flat index d*16+ps
      int d = j >> 4, ps = j & 15;
      float s = 0.f;
#pragma unroll
      for (int c = 0; c < 32; ++c)
        s = fmaf(rowl[(c << 4) + ps], w2l[(c << 5) + d], s);
      int ch = (tap << 4) + (j >> 5);
      int kin = j & 31;
      int p = (kin >> 3) ^ ((cc >> 1) & 3);
      size_t idx = ((((size_t)(nt * 144 + ch)) * 128 + cc) * 4 + p) * 8 + (kin & 7);
      Wf[idx] = f2bf(s);
    }
  } else {
#pragma unroll
    for (int i = 0; i < 2; ++i) {
      int j = (t << 1) + i;
      int ch = (tap << 4) + (j >> 5);
      int kin = j & 31;
      int p = (kin >> 3) ^ ((cc >> 1) & 3);
      size_t idx = ((((size_t)(nt * 144 + ch)) * 128 + cc) * 4 + p) * 8 + (kin & 7);
      Wf[idx] = 0;
    }
  }
}

// ---------------------------------------------------------------------------
// Wa conversion (unchanged R4 mapping): [ob(6)][ch(5)][nt(3)][ks(4)][lane][8]
__global__ __launch_bounds__(256) void wa_cvt_kernel(
    const float* __restrict__ w2, u16* __restrict__ Wa)
{
  int s2 = blockIdx.x * 256 + threadIdx.x;    // < 23040 (90 blocks)
  int cb = s2 / 768, si = s2 - cb * 768;
  int ob = cb / 5, ch = cb - ob * 5;
  int nt = si >> 8, ks = (si >> 6) & 3, l2 = si & 63;
  int o = ob * 96 + (nt << 5) + (l2 & 31);
  int kf = (ch << 6) + (ks << 4) + ((l2 >> 5) << 3);
  u16* dst = Wa + (size_t)s2 * 8;
#pragma unroll
  for (int e = 0; e < 8; ++e) {
    int k = kf + e;
    float v = (o < 544 && k < 288) ? w2[(size_t)o * 4896 + 4608 + k] : 0.f;
    dst[e] = f2bf(v);
  }
}

// ---------------------------------------------------------------------------
// g (R19): per input pixel emit u[j]=act[d]*(nrm scrambled), j=d*16+ps.
// No matmul (folded into Wf). Phase 3 = ut -> Ub bf16 coalesced copy.
__global__ __launch_bounds__(256) void g_kernel(
    const float* __restrict__ x, const float* __restrict__ ws,
    u16* __restrict__ Ub)
{
  __shared__ __align__(16) float raw[16][545];
  __shared__ __align__(16) float ut[16][576];
  __shared__ float mus[32], rss[32];
  int t = threadIdx.x;
  int pb = blockIdx.x;
  int b = pb >> 8, hi = (pb >> 2) & 63, wi0 = (pb & 3) << 4;

  {  // float4 loads — lane covers 4 adjacent pixels of one channel.
    int ch4 = t >> 2, wl4 = (t & 3) << 2;
    size_t gbase = ((size_t)b * 544) << 12;
    size_t rowoff = ((size_t)hi << 6) + (size_t)(wi0 + wl4);
    for (int it = 0; it < 9; ++it) {
      int ch = it * 64 + ch4;
      if (ch < 544) {
        float4 v = *reinterpret_cast<const float4*>(
            &x[gbase + ((size_t)ch << 12) + rowoff]);
        raw[wl4 + 0][ch] = v.x;
        raw[wl4 + 1][ch] = v.y;
        raw[wl4 + 2][ch] = v.z;
        raw[wl4 + 3][ch] = v.w;
      }
    }
  }
  if (t < 32) { mus[t] = ws[O_MU + b * 32 + t]; rss[t] = ws[O_RSTD + b * 32 + t]; }
  __syncthreads();

  {  // u values (validated indexing): ut[pix][psp*36+dp] = u[dp*16+psp]
    int dl = t & 15, psp = t >> 4;
    for (int it = 0; it < 32; ++it) {
      int pix = it >> 1, half = it & 1;
      int dp = half * 16 + dl;
      int j = (dp << 4) + psp;
      int cbv = j & 31, psv = j >> 5;
      float val = (raw[pix][(cbv << 4) + psv] - mus[cbv]) * rss[cbv];
      ut[pix][psp * 36 + dp] = raw[pix][512 + dp] * val;
    }
  }
  __syncthreads();

  {  // ut -> Ub bf16, coalesced u32 writes (2 u16 per thread per pixel)
    u16* Up = Ub + ((size_t)((((b << 6) + hi) << 6) + wi0)) * 512;
    int j0 = t << 1;
    int a0 = (j0 & 15) * 36 + (j0 >> 4);
    int a1 = ((j0 + 1) & 15) * 36 + ((j0 + 1) >> 4);
    for (int pix = 0; pix < 16; ++pix) {
      float v0 = ut[pix][a0];
      float v1 = ut[pix][a1];
      unsigned pack = (unsigned)f2bf(v0) | ((unsigned)f2bf(v1) << 16);
      *reinterpret_cast<unsigned*>(Up + (size_t)pix * 512 + j0) = pack;
    }
  }
}

// ---------------------------------------------------------------------------
// Fused GEMM (R15/R17 proven config, unchanged): M=8192 (64 mt), N=1024
// (8 nt, nt=7 zero-pad), K=4608 (144 BK=32). Grid 512 = 2 blocks/CU uniform.
// 256 thr = 4 waves (2x2), wave tile 64x64. Ring-3 counted-vmcnt loop.
// Epilogue: plain stores — o<288: BN1+sigmoid -> Aact; 288<=o<832: partC2.
__global__ __launch_bounds__(256) void gemm_fused(
    const u16* __restrict__ Ubp, const u16* __restrict__ Wf,
    const float* __restrict__ wsf, u16* __restrict__ Aact,
    float* __restrict__ partC2)
{
  __shared__ __align__(16) u16 AlA[3][4096];   // 8 KB each: row r at u16 r*32
  __shared__ __align__(16) u16 AlB[3][4096];   // col c at u16 c*32
  const int t = threadIdx.x;
  const int w = t >> 6, l = t & 63;
  const int wtm = w & 1, wtn = w >> 1;
  int bx = blockIdx.x;
  int xcd = bx & 7, idx = bx >> 3;          // idx < 64
  int mloc = idx & 7, nt = idx >> 3;        // mloc 0..7, nt 0..7
  int mt = (xcd << 3) + mloc;               // 0..63
  int p0 = mt << 7;

  size_t pixb[2]; int hb[2], wb[2], qa[2], dof[2];
#pragma unroll
  for (int g = 0; g < 2; ++g) {
    int r = (w << 5) + (g << 4) + (l >> 2);
    int pos = p0 + r;
    int b_ = pos >> 10, h_ = (pos >> 5) & 31, w_ = pos & 31;
    pixb[g] = ((size_t)b_) << 12;
    hb[g] = 2 * h_ - 1;
    wb[g] = 2 * w_ - 1;
    qa[g] = (((l & 3) ^ sfun(r)) << 3);
    dof[g] = ((w << 5) + (g << 4)) * 32 + (l << 3);
  }
  const u16* zb = (const u16*)(wsf + O_ZB);
  const u16* wfslab = Wf + ((size_t)(nt * 144)) * 4096;

  int aoffs[4], boffs[4];
#pragma unroll
  for (int f = 0; f < 4; ++f) {
    int r = (wtm << 6) + (f << 4) + (l & 15);
    aoffs[f] = r * 32 + ((((l >> 4)) ^ sfun(r)) << 3);
    int c = (wtn << 6) + (f << 4) + (l & 15);
    boffs[f] = c * 32 + ((((l >> 4)) ^ sfun(c)) << 3);
  }

  f32x4 acc[4][4];
#pragma unroll
  for (int i = 0; i < 4; ++i)
#pragma unroll
    for (int j = 0; j < 4; ++j) acc[i][j] = (f32x4){0.f, 0.f, 0.f, 0.f};

  auto stage = [&](int ch, int buf) {       // exactly 4 gll16 per wave
    int tap = ch >> 4;
    int kh = tap / 3, kw = tap - kh * 3;
    int cbase = (ch & 15) << 5;
#pragma unroll
    for (int g = 0; g < 2; ++g) {
      int hi = hb[g] + kh, wi = wb[g] + kw;
      bool ok = ((unsigned)hi < 64u) && ((unsigned)wi < 64u);
      const u16* src = ok
          ? (Ubp + ((pixb[g] + ((size_t)hi << 6) + (size_t)wi) << 9) + cbase + qa[g])
          : (zb + qa[g]);
      gll16(src, &AlA[buf][dof[g]]);
    }
    const u16* wsrc = wfslab + ((size_t)ch << 12);
#pragma unroll
    for (int g = 0; g < 2; ++g)
      gll16(wsrc + dof[g], &AlB[buf][dof[g]]);
  };

  stage(0, 0);
  stage(1, 1);

  int buf = 0;
  for (int n = 0; n < 144; ++n) {
    SB0();
    if (n < 143) asm volatile("s_waitcnt vmcnt(4)" ::: "memory");
    else         asm volatile("s_waitcnt vmcnt(0)" ::: "memory");
    SB0();
    __builtin_amdgcn_s_barrier();
    SB0();
    if (n + 2 < 144) {
      int nb = (buf >= 1) ? buf - 1 : 2;    // (buf+2)%3
      stage(n + 2, nb);
    }
    SB0();
    short8 aF[4], bF[4];
#pragma unroll
    for (int f = 0; f < 4; ++f) {
      aF[f] = *(const short8*)&AlA[buf][aoffs[f]];
      bF[f] = *(const short8*)&AlB[buf][boffs[f]];
    }
    __builtin_amdgcn_s_setprio(1);
#pragma unroll
    for (int fm = 0; fm < 4; ++fm)
#pragma unroll
      for (int fn = 0; fn < 4; ++fn)
        acc[fm][fn] = MFMA16(aF[fm], bF[fn], acc[fm][fn]);
    __builtin_amdgcn_s_setprio(0);
    buf = (buf == 2) ? 0 : buf + 1;
  }

  // epilogue: plain stores. C/D 16x16: col=l&15, row=(l>>4)*4+reg.
  const float* s1 = wsf + O_BN1S;
  const float* b1 = wsf + O_BN1B;
#pragma unroll
  for (int fn = 0; fn < 4; ++fn) {
    int o = nt * 128 + (wtn << 6) + (fn << 4) + (l & 15);
    if (o < 288) {
      float sc = s1[o], bi = b1[o];
#pragma unroll
      for (int fm = 0; fm < 4; ++fm) {
        int posr = p0 + (wtm << 6) + (fm << 4) + ((l >> 4) << 2);
#pragma unroll
        for (int r = 0; r < 4; ++r) {
          float z = acc[fm][fn][r] * sc + bi;
          float sg = 1.f / (1.f + expf(-z));
          Aact[(size_t)(posr + r) * 320 + o] = f2bf(sg);
        }
      }
    } else if (o < 832) {
#pragma unroll
      for (int fm = 0; fm < 4; ++fm) {
        int posr = p0 + (wtm << 6) + (fm << 4) + ((l >> 4) << 2);
#pragma unroll
        for (int r = 0; r < 4; ++r)
          partC2[(size_t)(posr + r) * 544 + (o - 288)] = acc[fm][fn][r];
      }
    }
  }
}

// ---------------------------------------------------------------------------
// Act GEMM: M=8192, N=576, K=320 (5 chunks). Unchanged.
__global__ __launch_bounds__(256, 2) void gemm_act(
    const u16* __restrict__ Aact, const u16* __restrict__ Wa,
    const float* __restrict__ partial, const float* __restrict__ wsf,
    float* __restrict__ outp)
{
  __shared__ __align__(16) char lraw[57344];          // 56 KB
  u16 (*AlA)[128 * 64] = (u16 (*)[128 * 64])lraw;     // 2 x 16 KB
  u16 (*AlB)[6144] = (u16 (*)[6144])(lraw + 32768);   // 2 x 12 KB
  float* T = (float*)lraw;                            // epilogue transpose
  const int t = threadIdx.x;
  const int wid = t >> 6, l = t & 63;
  int bx = blockIdx.x;
  int xcd = bx & 7, idx = bx >> 3;          // idx < 48
  int mt = xcd + ((idx & 7) << 3);
  int ob = idx >> 3;                        // 0..5
  int p0 = mt << 7;

  const u16* abase[4];
  int srow[4];
#pragma unroll
  for (int s = 0; s < 4; ++s) {
    int r = (wid << 5) + (s << 3) + (l >> 3);
    int jsw = ((l & 7) ^ (r & 7)) << 3;
    srow[s] = (wid << 5) + (s << 3);
    abase[s] = Aact + (size_t)(p0 + r) * 320 + jsw;
  }
  const u16* wslice = Wa + (size_t)(ob * 5) * 6144;
  const int bsub = (wid << 9) + (l << 3);

  f32x16 acc0 = {}, acc1 = {}, acc2 = {};

  auto stageA = [&](int ch, u16* lbuf) {
#pragma unroll
    for (int s = 0; s < 4; ++s)
      gll16(abase[s] + (ch << 6), lbuf + (srow[s] << 6));
  };
  auto stageB = [&](int ch, u16* lbuf) {
    const u16* src = wslice + (size_t)ch * 6144 + bsub;
#pragma unroll
    for (int c = 0; c < 3; ++c)
      gll16(src + (c << 11), lbuf + (c << 11) + (wid << 9));
  };
  const int rr = (wid << 5) + (l & 31);
  auto ldsA = [&](const u16* lbuf, short8* av) {
#pragma unroll
    for (int ks = 0; ks < 4; ++ks) {
      int jl = (ks << 1) + (l >> 5);
      av[ks] = *(const short8*)(lbuf + (rr << 6) + ((jl ^ (rr & 7)) << 3));
    }
  };
  auto ldsB = [&](const u16* lbuf, short8* bf) {
#pragma unroll
    for (int k2 = 0; k2 < 12; ++k2)
      bf[k2] = *(const short8*)(lbuf + (k2 << 9) + (l << 3));
  };
  auto mfmaR = [&](const short8* av, const short8* bf) {
    __builtin_amdgcn_s_setprio(1);
#pragma unroll
    for (int ks = 0; ks < 4; ++ks) {
      acc0 = MFMA32(av[ks], bf[ks], acc0);
      acc1 = MFMA32(av[ks], bf[4 + ks], acc1);
      acc2 = MFMA32(av[ks], bf[8 + ks], acc2);
    }
    __builtin_amdgcn_s_setprio(0);
  };

  short8 av[4], bf[12];

  stageA(0, AlA[0]);
  stageB(0, AlB[0]);
  asm volatile("s_waitcnt vmcnt(0)" ::: "memory");
  __builtin_amdgcn_s_barrier();

#define APHASE(K, CUR, NXT)                                                   \
  SB0();                                                                      \
  if ((K) + 1 < 5) { stageA((K) + 1, AlA[NXT]); stageB((K) + 1, AlB[NXT]); }  \
  SB0();                                                                      \
  ldsA(AlA[CUR], av);                                                         \
  ldsB(AlB[CUR], bf);                                                         \
  SB0();                                                                      \
  mfmaR(av, bf);                                                              \
  SB0();                                                                      \
  asm volatile("s_waitcnt vmcnt(0)" ::: "memory");                            \
  __builtin_amdgcn_s_barrier();

  APHASE(0, 0, 1);
  APHASE(1, 1, 0);
  APHASE(2, 0, 1);
  APHASE(3, 1, 0);
  APHASE(4, 0, 1);
#undef APHASE

  __syncthreads();   // protect T-union overwrite of staging LDS

  const float* s2p = wsf + O_BN2S;
  const float* b2p = wsf + O_BN2B;
#pragma unroll
  for (int nt = 0; nt < 3; ++nt) {
    int ol = (nt << 5) + (l & 31);
    int o = ob * 96 + ol;
    float sc = 0.f, bi = 0.f;
    if (o < 544) { sc = s2p[o]; bi = b2p[o]; }
    f32x16 a = (nt == 0) ? acc0 : ((nt == 1) ? acc1 : acc2);
#pragma unroll
    for (int reg = 0; reg < 16; ++reg) {
      int rowD = (reg & 3) + ((reg >> 2) << 3) + ((l >> 5) << 2);
      int pos = p0 + (wid << 5) + rowD;
      float pz = 0.f;
      if (o < 544) pz = partial[(size_t)pos * 544 + o];
      float z = (a[reg] + pz) * sc + bi;
      T[ol * 129 + (wid << 5) + rowD] = fmaxf(z, 0.f);
    }
  }
  __syncthreads();
  for (int s2 = t; s2 < 3072; s2 += 256) {
    int ol = s2 >> 5, c4 = s2 & 31;
    int o = ob * 96 + ol;
    if (o < 544) {
      int pos0 = p0 + (c4 << 2);
      int bb = pos0 >> 10, hw0 = pos0 & 1023;
      int base = ol * 129 + (c4 << 2);
      float4 v;
      v.x = T[base]; v.y = T[base + 1]; v.z = T[base + 2]; v.w = T[base + 3];
      *(float4*)&outp[(((size_t)(bb * 544 + o)) << 10) + hw0] = v;
    }
  }
}

// ---------------------------------------------------------------------------
extern "C" void kernel_launch(void* const* d_in, const int* in_sizes, int n_in,
                              void* d_out, int out_size, void* d_ws,
                              size_t ws_size, hipStream_t stream)
{
  const float* x       = (const float*)d_in[0];
  const float* wts     = (const float*)d_in[1];
  const float* gamma   = (const float*)d_in[2];
  const float* conv1_w = (const float*)d_in[3];
  const float* bn1s    = (const float*)d_in[4];
  const float* bn1b    = (const float*)d_in[5];
  const float* bn1m    = (const float*)d_in[6];
  const float* bn1v    = (const float*)d_in[7];
  const float* conv2_w = (const float*)d_in[8];
  const float* bn2s    = (const float*)d_in[9];
  const float* bn2b    = (const float*)d_in[10];
  const float* bn2m    = (const float*)d_in[11];
  const float* bn2v    = (const float*)d_in[12];

  char* wsb = (char*)d_ws;
  float* wsf = (float*)d_ws;
  u16* Ub    = (u16*)(wsb + O_G_B);
  u16* Aact  = (u16*)(wsb + O_AACT_B);
  float* prt = (float*)(wsb + O_PART_B);
  u16* Wf    = (u16*)(wsb + O_WF_B);
  u16* Wa    = (u16*)(wsb + O_WA_B);
  float* out = (float*)d_out;

  prep_kernel<<<1, 256, 0, stream>>>(wts, gamma, bn1s, bn1b, bn1m, bn1v,
                                     bn2s, bn2b, bn2m, bn2v, wsf);
  stats_kernel<<<256, 1024, 0, stream>>>(x, wsf, Aact);
  wcvt_kernel<<<9216, 256, 0, stream>>>(conv1_w, conv2_w, wsf, Wf);
  wa_cvt_kernel<<<90, 256, 0, stream>>>(conv2_w, Wa);
  g_kernel<<<2048, 256, 0, stream>>>(x, wsf, Ub);
  gemm_fused<<<512, 256, 0, stream>>>(Ub, Wf, wsf, Aact, prt);
  gemm_act<<<384, 256, 0, stream>>>(Aact, Wa, prt, wsf, out);
}